// Round 1
// baseline (532.114 us; speedup 1.0000x reference)
//
#include <hip/hip_runtime.h>
#include <stdint.h>

typedef short bf16x8_t __attribute__((ext_vector_type(8)));
typedef float f32x4_t __attribute__((ext_vector_type(4)));
typedef unsigned short u16x4_t __attribute__((ext_vector_type(4)));

#define DEV static __device__ __forceinline__

DEV float bf2f(unsigned short u) {
  union { unsigned int i; float f; } v; v.i = ((unsigned int)u) << 16; return v.f;
}
// round-to-nearest-even fp32 -> bf16
DEV unsigned short f2bf(float f) {
  union { float f; unsigned int i; } v; v.f = f;
  unsigned int x = v.i;
  unsigned int lsb = (x >> 16) & 1u;
  x += 0x7fffu + lsb;
  return (unsigned short)(x >> 16);
}

// ---------------------------------------------------------------------------
// fp32 -> bf16 convert (vectorized x4)
__global__ __launch_bounds__(256) void cvt_f32_bf16_k(
    const float* __restrict__ src, unsigned short* __restrict__ dst, int n4) {
  int i = blockIdx.x * 256 + threadIdx.x;
  if (i >= n4) return;
  float4 val = ((const float4*)src)[i];
  u16x4_t o = { f2bf(val.x), f2bf(val.y), f2bf(val.z), f2bf(val.w) };
  *(u16x4_t*)&dst[i * 4] = o;
}

// Build combined B matrix [4224 x 1024] bf16: rows 0..4095 = Wm, 4096..4159 = U,
// 4160..4223 = zeros (pad so N divisible by 128).
__global__ __launch_bounds__(256) void build_comb_k(
    const float* __restrict__ Wm, const float* __restrict__ U,
    unsigned short* __restrict__ dst) {
  int i = blockIdx.x * 256 + threadIdx.x;   // vec4 index; total 4224*1024/4
  int e = i * 4;
  int row = e >> 10;
  int k = e & 1023;
  float4 v;
  if (row < 4096)      v = *(const float4*)&Wm[(size_t)row * 1024 + k];
  else if (row < 4160) v = *(const float4*)&U[(size_t)(row - 4096) * 1024 + k];
  else                 v = make_float4(0.f, 0.f, 0.f, 0.f);
  u16x4_t o = { f2bf(v.x), f2bf(v.y), f2bf(v.z), f2bf(v.w) };
  *(u16x4_t*)&dst[e] = o;
}

// ---------------------------------------------------------------------------
// GEMM: C[M x N] = A[M x K] * B[N x K]^T  (both operands bf16, row-major,
// K-contiguous — the "gemm_bt" shape). 128x128 tile, BK=64, 4 waves (2x2),
// each wave 64x64 = 4x4 fragments of 16x16x32 MFMA.
// XOR-swizzled LDS (slot = kb ^ (row&7)) keeps ds_read_b128 ~conflict-free
// while respecting global_load_lds's wave-uniform-base + lane*16 placement.
template <int OUTF32, int RELU, int BIAS>
__global__ __launch_bounds__(256, 2) void gemm_bt(
    const unsigned short* __restrict__ A, const unsigned short* __restrict__ B,
    const float* __restrict__ bias, void* __restrict__ Cout,
    int M, int N, int K) {
  __shared__ unsigned short As[128 * 64];
  __shared__ unsigned short Bs[128 * 64];

  const int tid = threadIdx.x;
  const int lane = tid & 63;
  const int w = tid >> 6;
  const int wrow0 = (w & 1) * 64;
  const int wcol0 = (w >> 1) * 64;
  const int rowBase = blockIdx.y * 128;
  const int colBase = blockIdx.x * 128;

  // staging-load lane mapping: 8 rows x 8 slots of 8 bf16 per wave-issue
  const int rl = lane >> 3;       // row within 8-row group
  const int kbs = lane & 7;       // LDS kb slot
  const int kbg = kbs ^ rl;       // swizzled global kb

  // fragment-read lane mapping
  const int fr = lane & 15;
  const int quad = lane >> 4;

  f32x4_t acc[4][4];
#pragma unroll
  for (int i = 0; i < 4; i++)
#pragma unroll
    for (int j = 0; j < 4; j++) acc[i][j] = f32x4_t{0.f, 0.f, 0.f, 0.f};

  for (int kt = 0; kt < K; kt += 64) {
    __syncthreads();  // prior iter's readers done before overwrite
#pragma unroll
    for (int jj = 0; jj < 4; ++jj) {
      int tr = w * 32 + jj * 8 + rl;
      const unsigned short* ga = A + (size_t)(rowBase + tr) * K + kt + kbg * 8;
      const unsigned short* gb = B + (size_t)(colBase + tr) * K + kt + kbg * 8;
      __builtin_amdgcn_global_load_lds(
          (const __attribute__((address_space(1))) void*)ga,
          (__attribute__((address_space(3))) void*)&As[(w * 32 + jj * 8) * 64],
          16, 0, 0);
      __builtin_amdgcn_global_load_lds(
          (const __attribute__((address_space(1))) void*)gb,
          (__attribute__((address_space(3))) void*)&Bs[(w * 32 + jj * 8) * 64],
          16, 0, 0);
    }
    __syncthreads();  // drains vmcnt, then barrier: tile visible to all

#pragma unroll
    for (int ks = 0; ks < 2; ++ks) {
      bf16x8_t a[4], b[4];
#pragma unroll
      for (int i = 0; i < 4; i++) {
        int m = wrow0 + i * 16 + fr;
        int slot = (ks * 4 + quad) ^ (m & 7);
        a[i] = *(const bf16x8_t*)&As[m * 64 + slot * 8];
      }
#pragma unroll
      for (int j = 0; j < 4; j++) {
        int n = wcol0 + j * 16 + fr;
        int slot = (ks * 4 + quad) ^ (n & 7);
        b[j] = *(const bf16x8_t*)&Bs[n * 64 + slot * 8];
      }
#pragma unroll
      for (int i = 0; i < 4; i++)
#pragma unroll
        for (int j = 0; j < 4; j++)
          acc[i][j] = __builtin_amdgcn_mfma_f32_16x16x32_bf16(a[i], b[j],
                                                              acc[i][j], 0, 0, 0);
    }
  }

  // epilogue: C/D layout col=lane&15, row=quad*4+reg (m89-verified)
#pragma unroll
  for (int j = 0; j < 4; j++) {
    int col = colBase + wcol0 + j * 16 + fr;
    float bv = BIAS ? bias[col] : 0.0f;
#pragma unroll
    for (int i = 0; i < 4; i++) {
#pragma unroll
      for (int r = 0; r < 4; r++) {
        int row = rowBase + wrow0 + i * 16 + quad * 4 + r;
        float v = acc[i][j][r] + bv;
        if (RELU) v = v > 0.f ? v : 0.f;
        if (OUTF32)
          ((float*)Cout)[(size_t)row * N + col] = v;
        else
          ((unsigned short*)Cout)[(size_t)row * N + col] = f2bf(v);
      }
    }
  }
}

// ---------------------------------------------------------------------------
// h[b,s] = sum_r u[b,r] * (W'[b, r*64+s] + bm[r*64+s]);  u[b,r] = W'[b, 4096+r]
// W' is [8192 x 4224] bf16. One wave per sample (lane = s), 4 samples/block.
__global__ __launch_bounds__(256) void contract_k(
    const unsigned short* __restrict__ Wp, const float* __restrict__ bm,
    unsigned short* __restrict__ h) {
  const int s = threadIdx.x & 63;
  const int b = blockIdx.x * 4 + (threadIdx.x >> 6);
  const unsigned short* wrow = Wp + (size_t)b * 4224;
  float acc = 0.f;
#pragma unroll 8
  for (int r = 0; r < 64; ++r) {
    float u = bf2f(wrow[4096 + r]);              // broadcast within wave
    float wv = bf2f(wrow[r * 64 + s]) + bm[r * 64 + s];
    acc += u * wv;
  }
  h[(size_t)b * 64 + s] = f2bf(acc);
}

// ---------------------------------------------------------------------------
extern "C" void kernel_launch(void* const* d_in, const int* in_sizes, int n_in,
                              void* d_out, int out_size, void* d_ws,
                              size_t ws_size, hipStream_t stream) {
  const float* x = (const float*)d_in[0];
  const float* Wm[3] = {(const float*)d_in[1], (const float*)d_in[6], (const float*)d_in[11]};
  const float* bm[3] = {(const float*)d_in[2], (const float*)d_in[7], (const float*)d_in[12]};
  const float* U[3]  = {(const float*)d_in[3], (const float*)d_in[8], (const float*)d_in[13]};
  const float* V[3]  = {(const float*)d_in[4], (const float*)d_in[9], (const float*)d_in[14]};
  const float* bs[3] = {(const float*)d_in[5], (const float*)d_in[10], (const float*)d_in[15]};

  char* p = (char*)d_ws;
  unsigned short* xb = (unsigned short*)p;  p += 8192UL * 1024 * 2;
  unsigned short* act = (unsigned short*)p; p += 8192UL * 1024 * 2;
  unsigned short* Bc[3];
  for (int l = 0; l < 3; l++) { Bc[l] = (unsigned short*)p; p += 4224UL * 1024 * 2; }
  unsigned short* Vb[3];
  for (int l = 0; l < 3; l++) { Vb[l] = (unsigned short*)p; p += 1024UL * 64 * 2; }
  unsigned short* hb = (unsigned short*)p;  p += 8192UL * 64 * 2;
  unsigned short* Wbuf = (unsigned short*)p; p += 8192UL * 4224 * 2;

  // upfront conversions
  cvt_f32_bf16_k<<<8192, 256, 0, stream>>>(x, xb, 8192 * 1024 / 4);
  for (int l = 0; l < 3; l++)
    build_comb_k<<<4224, 256, 0, stream>>>(Wm[l], U[l], Bc[l]);
  for (int l = 0; l < 3; l++)
    cvt_f32_bf16_k<<<64, 256, 0, stream>>>(V[l], Vb[l], 1024 * 64 / 4);

  const unsigned short* cur = xb;
  for (int l = 0; l < 3; l++) {
    // W' = cur @ Bc^T : [8192 x 4224]  (cols 0..4095 = w, 4096..4159 = u)
    gemm_bt<0, 0, 0><<<dim3(33, 64), 256, 0, stream>>>(
        cur, Bc[l], nullptr, Wbuf, 8192, 4224, 1024);
    // h = einsum('br,brs->bs', u, w + bm)
    contract_k<<<2048, 256, 0, stream>>>(Wbuf, bm[l], hb);
    if (l < 2) {
      // act = relu(h @ V^T + b), bf16
      gemm_bt<0, 1, 1><<<dim3(8, 64), 256, 0, stream>>>(
          hb, Vb[l], bs[l], act, 8192, 1024, 64);
      cur = act;
    } else {
      // out = h @ V^T + b, fp32
      gemm_bt<1, 0, 1><<<dim3(8, 64), 256, 0, stream>>>(
          hb, Vb[2], bs[2], d_out, 8192, 1024, 64);
    }
  }
}

// Round 2
// 464.582 us; speedup vs baseline: 1.1454x; 1.1454x over previous
//
#include <hip/hip_runtime.h>
#include <stdint.h>

typedef short bf16x8_t __attribute__((ext_vector_type(8)));
typedef short bf16x4_t __attribute__((ext_vector_type(4)));
typedef float f32x4_t __attribute__((ext_vector_type(4)));
typedef unsigned short u16x4_t __attribute__((ext_vector_type(4)));

#define DEV static __device__ __forceinline__

DEV float bf2f(unsigned short u) {
  union { unsigned int i; float f; } v; v.i = ((unsigned int)u) << 16; return v.f;
}
// round-to-nearest-even fp32 -> bf16
DEV unsigned short f2bf(float f) {
  union { float f; unsigned int i; } v; v.f = f;
  unsigned int x = v.i;
  unsigned int lsb = (x >> 16) & 1u;
  x += 0x7fffu + lsb;
  return (unsigned short)(x >> 16);
}

// ---------------------------------------------------------------------------
// fp32 -> bf16 convert (vectorized x4)
__global__ __launch_bounds__(256) void cvt_f32_bf16_k(
    const float* __restrict__ src, unsigned short* __restrict__ dst, int n4) {
  int i = blockIdx.x * 256 + threadIdx.x;
  if (i >= n4) return;
  float4 val = ((const float4*)src)[i];
  u16x4_t o = { f2bf(val.x), f2bf(val.y), f2bf(val.z), f2bf(val.w) };
  *(u16x4_t*)&dst[i * 4] = o;
}

// U [64 x 1024] fp32 -> Ub [128 x 1024] bf16 (rows 64..127 zero-padded)
__global__ __launch_bounds__(256) void build_u_k(
    const float* __restrict__ U, unsigned short* __restrict__ dst) {
  int i = blockIdx.x * 256 + threadIdx.x;   // vec4 index over 128*1024
  int e = i * 4;
  int row = e >> 10;
  int k = e & 1023;
  float4 v = (row < 64) ? *(const float4*)&U[(size_t)row * 1024 + k]
                        : make_float4(0.f, 0.f, 0.f, 0.f);
  u16x4_t o = { f2bf(v.x), f2bf(v.y), f2bf(v.z), f2bf(v.w) };
  *(u16x4_t*)&dst[e] = o;
}

// ---------------------------------------------------------------------------
// Generic GEMM: C[M x N] = A[M x K] * B[N x K]^T (bf16 in, K-contiguous).
// 128x128 tile, BK=64, 4 waves (2x2), 16x16x32 MFMA, XOR-swizzled LDS.
template <int OUTF32, int RELU, int BIAS>
__global__ __launch_bounds__(256, 2) void gemm_bt(
    const unsigned short* __restrict__ A, const unsigned short* __restrict__ B,
    const float* __restrict__ bias, void* __restrict__ Cout,
    int M, int N, int K) {
  __shared__ unsigned short As[128 * 64];
  __shared__ unsigned short Bs[128 * 64];

  const int tid = threadIdx.x;
  const int lane = tid & 63;
  const int w = tid >> 6;
  const int wrow0 = (w & 1) * 64;
  const int wcol0 = (w >> 1) * 64;
  const int rowBase = blockIdx.y * 128;
  const int colBase = blockIdx.x * 128;

  const int rl = lane >> 3;
  const int kbs = lane & 7;
  const int kbg = kbs ^ rl;

  const int fr = lane & 15;
  const int quad = lane >> 4;

  f32x4_t acc[4][4];
#pragma unroll
  for (int i = 0; i < 4; i++)
#pragma unroll
    for (int j = 0; j < 4; j++) acc[i][j] = f32x4_t{0.f, 0.f, 0.f, 0.f};

  for (int kt = 0; kt < K; kt += 64) {
    __syncthreads();
#pragma unroll
    for (int jj = 0; jj < 4; ++jj) {
      int tr = w * 32 + jj * 8 + rl;
      const unsigned short* ga = A + (size_t)(rowBase + tr) * K + kt + kbg * 8;
      const unsigned short* gb = B + (size_t)(colBase + tr) * K + kt + kbg * 8;
      __builtin_amdgcn_global_load_lds(
          (const __attribute__((address_space(1))) void*)ga,
          (__attribute__((address_space(3))) void*)&As[(w * 32 + jj * 8) * 64],
          16, 0, 0);
      __builtin_amdgcn_global_load_lds(
          (const __attribute__((address_space(1))) void*)gb,
          (__attribute__((address_space(3))) void*)&Bs[(w * 32 + jj * 8) * 64],
          16, 0, 0);
    }
    __syncthreads();

#pragma unroll
    for (int ks = 0; ks < 2; ++ks) {
      bf16x8_t a[4], b[4];
#pragma unroll
      for (int i = 0; i < 4; i++) {
        int m = wrow0 + i * 16 + fr;
        int slot = (ks * 4 + quad) ^ (m & 7);
        a[i] = *(const bf16x8_t*)&As[m * 64 + slot * 8];
      }
#pragma unroll
      for (int j = 0; j < 4; j++) {
        int n = wcol0 + j * 16 + fr;
        int slot = (ks * 4 + quad) ^ (n & 7);
        b[j] = *(const bf16x8_t*)&Bs[n * 64 + slot * 8];
      }
#pragma unroll
      for (int i = 0; i < 4; i++)
#pragma unroll
        for (int j = 0; j < 4; j++)
          acc[i][j] = __builtin_amdgcn_mfma_f32_16x16x32_bf16(a[i], b[j],
                                                              acc[i][j], 0, 0, 0);
    }
  }

#pragma unroll
  for (int j = 0; j < 4; j++) {
    int col = colBase + wcol0 + j * 16 + fr;
    float bv = BIAS ? bias[col] : 0.0f;
#pragma unroll
    for (int i = 0; i < 4; i++) {
#pragma unroll
      for (int r = 0; r < 4; r++) {
        int row = rowBase + wrow0 + i * 16 + quad * 4 + r;
        float v = acc[i][j][r] + bv;
        if (RELU) v = v > 0.f ? v : 0.f;
        if (OUTF32)
          ((float*)Cout)[(size_t)row * N + col] = v;
        else
          ((unsigned short*)Cout)[(size_t)row * N + col] = f2bf(v);
      }
    }
  }
}

// ---------------------------------------------------------------------------
// Fused hyper-GEMM + per-sample contraction.
// Computes w' = A @ Wm^T with COLUMN PERMUTATION col' = s*64+r (tile row ct
// stages Wm row (ct&63)*64 + (ct>>6)), so each wave's 64 cols = all r for ONE
// s. Epilogue: h[b,s] = sum_r u[b,r] * (w'[b,s,r] + bm[r*64+s]), reduced
// in-wave via shfl_xor butterfly over the 16 fr-lanes. No W' materialized.
__global__ __launch_bounds__(256, 2) void gemm_fused(
    const unsigned short* __restrict__ A,    // [8192 x 1024] bf16
    const unsigned short* __restrict__ Wmb,  // [4096 x 1024] bf16
    const unsigned short* __restrict__ ug,   // [8192 x 128] bf16 (cols 0..63 = u)
    const float* __restrict__ bm,            // [4096] fp32
    unsigned short* __restrict__ h_out) {    // [8192 x 64] bf16
  __shared__ unsigned short smem[16384];     // As | Bs, reused for u_t
  unsigned short* As = smem;
  unsigned short* Bs = smem + 8192;
  const int K = 1024;

  const int tid = threadIdx.x;
  const int lane = tid & 63;
  const int w = tid >> 6;
  const int wrow0 = (w & 1) * 64;
  const int wcol0 = (w >> 1) * 64;
  const int rowBase = blockIdx.y * 128;
  const int colBase = blockIdx.x * 128;

  const int rl = lane >> 3;
  const int kbs = lane & 7;
  const int kbg = kbs ^ rl;

  const int fr = lane & 15;
  const int quad = lane >> 4;

  f32x4_t acc[4][4];
#pragma unroll
  for (int i = 0; i < 4; i++)
#pragma unroll
    for (int j = 0; j < 4; j++) acc[i][j] = f32x4_t{0.f, 0.f, 0.f, 0.f};

  for (int kt = 0; kt < K; kt += 64) {
    __syncthreads();
#pragma unroll
    for (int jj = 0; jj < 4; ++jj) {
      int tr = w * 32 + jj * 8 + rl;
      int ct = colBase + tr;
      int pr = ((ct & 63) << 6) | (ct >> 6);  // Wm row for hyper-col ct
      const unsigned short* ga = A + (size_t)(rowBase + tr) * K + kt + kbg * 8;
      const unsigned short* gb = Wmb + (size_t)pr * K + kt + kbg * 8;
      __builtin_amdgcn_global_load_lds(
          (const __attribute__((address_space(1))) void*)ga,
          (__attribute__((address_space(3))) void*)&As[(w * 32 + jj * 8) * 64],
          16, 0, 0);
      __builtin_amdgcn_global_load_lds(
          (const __attribute__((address_space(1))) void*)gb,
          (__attribute__((address_space(3))) void*)&Bs[(w * 32 + jj * 8) * 64],
          16, 0, 0);
    }
    __syncthreads();

#pragma unroll
    for (int ks = 0; ks < 2; ++ks) {
      bf16x8_t a[4], b[4];
#pragma unroll
      for (int i = 0; i < 4; i++) {
        int m = wrow0 + i * 16 + fr;
        int slot = (ks * 4 + quad) ^ (m & 7);
        a[i] = *(const bf16x8_t*)&As[m * 64 + slot * 8];
      }
#pragma unroll
      for (int j = 0; j < 4; j++) {
        int n = wcol0 + j * 16 + fr;
        int slot = (ks * 4 + quad) ^ (n & 7);
        b[j] = *(const bf16x8_t*)&Bs[n * 64 + slot * 8];
      }
#pragma unroll
      for (int i = 0; i < 4; i++)
#pragma unroll
        for (int j = 0; j < 4; j++)
          acc[i][j] = __builtin_amdgcn_mfma_f32_16x16x32_bf16(a[i], b[j],
                                                              acc[i][j], 0, 0, 0);
    }
  }

  // ---- fused contraction epilogue ----
  __syncthreads();  // MFMA LDS readers done before u_t overwrites smem

  // stage u transposed: u_t[r][row], row-stride 136 (272 B) to spread banks
  {
    int row = tid >> 1;
    int c0 = (tid & 1) * 32;
    const unsigned short* up = ug + (size_t)(rowBase + row) * 128 + c0;
    bf16x8_t v0 = *(const bf16x8_t*)(up);
    bf16x8_t v1 = *(const bf16x8_t*)(up + 8);
    bf16x8_t v2 = *(const bf16x8_t*)(up + 16);
    bf16x8_t v3 = *(const bf16x8_t*)(up + 24);
#pragma unroll
    for (int m = 0; m < 8; m++) {
      smem[(c0 + m) * 136 + row] = (unsigned short)v0[m];
      smem[(c0 + 8 + m) * 136 + row] = (unsigned short)v1[m];
      smem[(c0 + 16 + m) * 136 + row] = (unsigned short)v2[m];
      smem[(c0 + 24 + m) * 136 + row] = (unsigned short)v3[m];
    }
  }
  __syncthreads();

  const int s = blockIdx.x * 2 + (w >> 1);  // this wave's s value
  float bmv[4];
#pragma unroll
  for (int j = 0; j < 4; j++) bmv[j] = bm[(j * 16 + fr) * 64 + s];

#pragma unroll
  for (int i = 0; i < 4; i++) {
    int row0 = wrow0 + i * 16 + quad * 4;
    bf16x4_t uv[4];
#pragma unroll
    for (int j = 0; j < 4; j++)
      uv[j] = *(const bf16x4_t*)&smem[(j * 16 + fr) * 136 + row0];
#pragma unroll
    for (int r = 0; r < 4; r++) {
      float p = 0.f;
#pragma unroll
      for (int j = 0; j < 4; j++)
        p += bf2f((unsigned short)uv[j][r]) * (acc[i][j][r] + bmv[j]);
      p += __shfl_xor(p, 1, 64);
      p += __shfl_xor(p, 2, 64);
      p += __shfl_xor(p, 4, 64);
      p += __shfl_xor(p, 8, 64);
      if (fr == 0)
        h_out[(size_t)(rowBase + row0 + r) * 64 + s] = f2bf(p);
    }
  }
}

// ---------------------------------------------------------------------------
extern "C" void kernel_launch(void* const* d_in, const int* in_sizes, int n_in,
                              void* d_out, int out_size, void* d_ws,
                              size_t ws_size, hipStream_t stream) {
  const float* x = (const float*)d_in[0];
  const float* Wm[3] = {(const float*)d_in[1], (const float*)d_in[6], (const float*)d_in[11]};
  const float* bm[3] = {(const float*)d_in[2], (const float*)d_in[7], (const float*)d_in[12]};
  const float* U[3]  = {(const float*)d_in[3], (const float*)d_in[8], (const float*)d_in[13]};
  const float* V[3]  = {(const float*)d_in[4], (const float*)d_in[9], (const float*)d_in[14]};
  const float* bs[3] = {(const float*)d_in[5], (const float*)d_in[10], (const float*)d_in[15]};

  char* p = (char*)d_ws;
  unsigned short* xb = (unsigned short*)p;  p += 8192UL * 1024 * 2;
  unsigned short* act = (unsigned short*)p; p += 8192UL * 1024 * 2;
  unsigned short* Wmb[3];
  for (int l = 0; l < 3; l++) { Wmb[l] = (unsigned short*)p; p += 4096UL * 1024 * 2; }
  unsigned short* Ub[3];
  for (int l = 0; l < 3; l++) { Ub[l] = (unsigned short*)p; p += 128UL * 1024 * 2; }
  unsigned short* Vb[3];
  for (int l = 0; l < 3; l++) { Vb[l] = (unsigned short*)p; p += 1024UL * 64 * 2; }
  unsigned short* hb = (unsigned short*)p;  p += 8192UL * 64 * 2;
  unsigned short* ug = (unsigned short*)p;  p += 8192UL * 128 * 2;

  // upfront conversions
  cvt_f32_bf16_k<<<8192, 256, 0, stream>>>(x, xb, 8192 * 1024 / 4);
  for (int l = 0; l < 3; l++) {
    cvt_f32_bf16_k<<<4096, 256, 0, stream>>>(Wm[l], Wmb[l], 4096 * 1024 / 4);
    build_u_k<<<128, 256, 0, stream>>>(U[l], Ub[l]);
    cvt_f32_bf16_k<<<64, 256, 0, stream>>>(V[l], Vb[l], 1024 * 64 / 4);
  }

  const unsigned short* cur = xb;
  for (int l = 0; l < 3; l++) {
    // u = cur @ U^T (padded to 128 cols; cols 64..127 come out zero)
    gemm_bt<0, 0, 0><<<dim3(1, 64), 256, 0, stream>>>(
        cur, Ub[l], nullptr, ug, 8192, 128, 1024);
    // fused: h = einsum('br,brs->bs', u, cur@Wm^T + bm)
    gemm_fused<<<dim3(32, 64), 256, 0, stream>>>(cur, Wmb[l], ug, bm[l], hb);
    if (l < 2) {
      gemm_bt<0, 1, 1><<<dim3(8, 64), 256, 0, stream>>>(
          hb, Vb[l], bs[l], act, 8192, 1024, 64);
      cur = act;
    } else {
      gemm_bt<1, 0, 1><<<dim3(8, 64), 256, 0, stream>>>(
          hb, Vb[2], bs[2], d_out, 8192, 1024, 64);
    }
  }
}

// Round 3
// 422.077 us; speedup vs baseline: 1.2607x; 1.1007x over previous
//
#include <hip/hip_runtime.h>
#include <stdint.h>

typedef short bf16x8_t __attribute__((ext_vector_type(8)));
typedef short bf16x4_t __attribute__((ext_vector_type(4)));
typedef float f32x4_t __attribute__((ext_vector_type(4)));
typedef unsigned short u16x4_t __attribute__((ext_vector_type(4)));

#define DEV static __device__ __forceinline__

DEV float bf2f(unsigned short u) {
  union { unsigned int i; float f; } v; v.i = ((unsigned int)u) << 16; return v.f;
}
DEV unsigned short f2bf(float f) {
  union { float f; unsigned int i; } v; v.f = f;
  unsigned int x = v.i;
  unsigned int lsb = (x >> 16) & 1u;
  x += 0x7fffu + lsb;
  return (unsigned short)(x >> 16);
}

// ---------------------------------------------------------------------------
// One dispatch converting ALL fp32 inputs to bf16. Segment boundaries are all
// multiples of 256 vec4s, so `seg` is block-uniform (stays scalar).
struct CvtTab {
  const float* src[10];
  unsigned short* dst[10];
  int bstart[10];  // segment start, in BLOCKS (256 vec4 each)
};

__global__ __launch_bounds__(256) void cvt_all_k(CvtTab t) {
  int bi = blockIdx.x;
  int seg = 0;
#pragma unroll
  for (int s = 1; s < 10; s++) seg += (bi >= t.bstart[s]) ? 1 : 0;
  int local = (bi - t.bstart[seg]) * 256 + threadIdx.x;
  const float* src = t.src[seg];
  unsigned short* dst = t.dst[seg];
  float4 v = ((const float4*)src)[local];
  u16x4_t o = { f2bf(v.x), f2bf(v.y), f2bf(v.z), f2bf(v.w) };
  *(u16x4_t*)&dst[local * 4] = o;
}

// ---------------------------------------------------------------------------
// Split-K u-GEMM: part[kslice] += A[128-row block] @ U^T, K-slice of 256.
// Grid (4 kslices, 64 rowblocks) = 256 blocks -> full GPU, vs 64 before.
__global__ __launch_bounds__(256, 2) void u_splitk(
    const unsigned short* __restrict__ A,   // [8192 x 1024] bf16
    const unsigned short* __restrict__ Ub,  // [64 x 1024] bf16
    float* __restrict__ part) {             // [4][8192][64] fp32
  __shared__ unsigned short As[128 * 64];
  __shared__ unsigned short Us[64 * 64];

  const int tid = threadIdx.x;
  const int lane = tid & 63;
  const int w = tid >> 6;
  const int rowBase = blockIdx.y * 128;
  const int kBase = blockIdx.x * 256;

  const int rl = lane >> 3;
  const int kbs = lane & 7;
  const int kbg = kbs ^ rl;
  const int fr = lane & 15;
  const int quad = lane >> 4;

  f32x4_t acc[2][4];
#pragma unroll
  for (int i = 0; i < 2; i++)
#pragma unroll
    for (int j = 0; j < 4; j++) acc[i][j] = f32x4_t{0.f, 0.f, 0.f, 0.f};

  for (int kt = kBase; kt < kBase + 256; kt += 64) {
    __syncthreads();
#pragma unroll
    for (int jj = 0; jj < 4; ++jj) {
      int tr = w * 32 + jj * 8 + rl;
      const unsigned short* ga = A + (size_t)(rowBase + tr) * 1024 + kt + kbg * 8;
      __builtin_amdgcn_global_load_lds(
          (const __attribute__((address_space(1))) void*)ga,
          (__attribute__((address_space(3))) void*)&As[(w * 32 + jj * 8) * 64],
          16, 0, 0);
    }
#pragma unroll
    for (int jj = 0; jj < 2; ++jj) {
      int tr = w * 16 + jj * 8 + rl;
      const unsigned short* gu = Ub + (size_t)tr * 1024 + kt + kbg * 8;
      __builtin_amdgcn_global_load_lds(
          (const __attribute__((address_space(1))) void*)gu,
          (__attribute__((address_space(3))) void*)&Us[(w * 16 + jj * 8) * 64],
          16, 0, 0);
    }
    __syncthreads();

#pragma unroll
    for (int ks = 0; ks < 2; ++ks) {
      bf16x8_t a[2], b[4];
#pragma unroll
      for (int i = 0; i < 2; i++) {
        int m = w * 32 + i * 16 + fr;
        int slot = (ks * 4 + quad) ^ (m & 7);
        a[i] = *(const bf16x8_t*)&As[m * 64 + slot * 8];
      }
#pragma unroll
      for (int j = 0; j < 4; j++) {
        int n = j * 16 + fr;
        int slot = (ks * 4 + quad) ^ (n & 7);
        b[j] = *(const bf16x8_t*)&Us[n * 64 + slot * 8];
      }
#pragma unroll
      for (int i = 0; i < 2; i++)
#pragma unroll
        for (int j = 0; j < 4; j++)
          acc[i][j] = __builtin_amdgcn_mfma_f32_16x16x32_bf16(a[i], b[j],
                                                              acc[i][j], 0, 0, 0);
    }
  }

  float* pp = part + ((size_t)blockIdx.x * 8192 + rowBase) * 64;
#pragma unroll
  for (int i = 0; i < 2; i++)
#pragma unroll
    for (int j = 0; j < 4; j++)
#pragma unroll
      for (int r = 0; r < 4; r++) {
        int row = w * 32 + i * 16 + quad * 4 + r;
        pp[(size_t)row * 64 + j * 16 + fr] = acc[i][j][r];
      }
}

// sum 4 K-slices -> bf16 u [8192 x 64]
__global__ __launch_bounds__(256) void u_reduce_k(
    const float* __restrict__ part, unsigned short* __restrict__ ug) {
  int i = blockIdx.x * 256 + threadIdx.x;  // vec4 idx over 131072
  float4 s0 = ((const float4*)part)[i];
  float4 s1 = ((const float4*)part)[i + 131072];
  float4 s2 = ((const float4*)part)[i + 262144];
  float4 s3 = ((const float4*)part)[i + 393216];
  u16x4_t o = { f2bf(s0.x + s1.x + s2.x + s3.x),
                f2bf(s0.y + s1.y + s2.y + s3.y),
                f2bf(s0.z + s1.z + s2.z + s3.z),
                f2bf(s0.w + s1.w + s2.w + s3.w) };
  *(u16x4_t*)&ug[i * 4] = o;
}

// ---------------------------------------------------------------------------
// Generic GEMM: C[M x N] = A[M x K] * B[N x K]^T (bf16 in, K-contiguous).
template <int OUTF32, int RELU, int BIAS>
__global__ __launch_bounds__(256, 2) void gemm_bt(
    const unsigned short* __restrict__ A, const unsigned short* __restrict__ B,
    const float* __restrict__ bias, void* __restrict__ Cout,
    int M, int N, int K) {
  __shared__ unsigned short As[128 * 64];
  __shared__ unsigned short Bs[128 * 64];

  const int tid = threadIdx.x;
  const int lane = tid & 63;
  const int w = tid >> 6;
  const int wrow0 = (w & 1) * 64;
  const int wcol0 = (w >> 1) * 64;
  const int rowBase = blockIdx.y * 128;
  const int colBase = blockIdx.x * 128;

  const int rl = lane >> 3;
  const int kbs = lane & 7;
  const int kbg = kbs ^ rl;
  const int fr = lane & 15;
  const int quad = lane >> 4;

  f32x4_t acc[4][4];
#pragma unroll
  for (int i = 0; i < 4; i++)
#pragma unroll
    for (int j = 0; j < 4; j++) acc[i][j] = f32x4_t{0.f, 0.f, 0.f, 0.f};

  for (int kt = 0; kt < K; kt += 64) {
    __syncthreads();
#pragma unroll
    for (int jj = 0; jj < 4; ++jj) {
      int tr = w * 32 + jj * 8 + rl;
      const unsigned short* ga = A + (size_t)(rowBase + tr) * K + kt + kbg * 8;
      const unsigned short* gb = B + (size_t)(colBase + tr) * K + kt + kbg * 8;
      __builtin_amdgcn_global_load_lds(
          (const __attribute__((address_space(1))) void*)ga,
          (__attribute__((address_space(3))) void*)&As[(w * 32 + jj * 8) * 64],
          16, 0, 0);
      __builtin_amdgcn_global_load_lds(
          (const __attribute__((address_space(1))) void*)gb,
          (__attribute__((address_space(3))) void*)&Bs[(w * 32 + jj * 8) * 64],
          16, 0, 0);
    }
    __syncthreads();

#pragma unroll
    for (int ks = 0; ks < 2; ++ks) {
      bf16x8_t a[4], b[4];
#pragma unroll
      for (int i = 0; i < 4; i++) {
        int m = wrow0 + i * 16 + fr;
        int slot = (ks * 4 + quad) ^ (m & 7);
        a[i] = *(const bf16x8_t*)&As[m * 64 + slot * 8];
      }
#pragma unroll
      for (int j = 0; j < 4; j++) {
        int n = wcol0 + j * 16 + fr;
        int slot = (ks * 4 + quad) ^ (n & 7);
        b[j] = *(const bf16x8_t*)&Bs[n * 64 + slot * 8];
      }
#pragma unroll
      for (int i = 0; i < 4; i++)
#pragma unroll
        for (int j = 0; j < 4; j++)
          acc[i][j] = __builtin_amdgcn_mfma_f32_16x16x32_bf16(a[i], b[j],
                                                              acc[i][j], 0, 0, 0);
    }
  }

#pragma unroll
  for (int j = 0; j < 4; j++) {
    int col = colBase + wcol0 + j * 16 + fr;
    float bv = BIAS ? bias[col] : 0.0f;
#pragma unroll
    for (int i = 0; i < 4; i++) {
#pragma unroll
      for (int r = 0; r < 4; r++) {
        int row = rowBase + wrow0 + i * 16 + quad * 4 + r;
        float v = acc[i][j][r] + bv;
        if (RELU) v = v > 0.f ? v : 0.f;
        if (OUTF32)
          ((float*)Cout)[(size_t)row * N + col] = v;
        else
          ((unsigned short*)Cout)[(size_t)row * N + col] = f2bf(v);
      }
    }
  }
}

// ---------------------------------------------------------------------------
// Fused hyper-GEMM + per-sample contraction (col' = s*64+r permutation).
__global__ __launch_bounds__(256, 2) void gemm_fused(
    const unsigned short* __restrict__ A,    // [8192 x 1024] bf16
    const unsigned short* __restrict__ Wmb,  // [4096 x 1024] bf16
    const unsigned short* __restrict__ ug,   // [8192 x 64] bf16
    const float* __restrict__ bm,            // [4096] fp32
    unsigned short* __restrict__ h_out) {    // [8192 x 64] bf16
  __shared__ unsigned short smem[16384];
  unsigned short* As = smem;
  unsigned short* Bs = smem + 8192;
  const int K = 1024;

  const int tid = threadIdx.x;
  const int lane = tid & 63;
  const int w = tid >> 6;
  const int wrow0 = (w & 1) * 64;
  const int wcol0 = (w >> 1) * 64;
  const int rowBase = blockIdx.y * 128;
  const int colBase = blockIdx.x * 128;

  const int rl = lane >> 3;
  const int kbs = lane & 7;
  const int kbg = kbs ^ rl;
  const int fr = lane & 15;
  const int quad = lane >> 4;

  f32x4_t acc[4][4];
#pragma unroll
  for (int i = 0; i < 4; i++)
#pragma unroll
    for (int j = 0; j < 4; j++) acc[i][j] = f32x4_t{0.f, 0.f, 0.f, 0.f};

  for (int kt = 0; kt < K; kt += 64) {
    __syncthreads();
#pragma unroll
    for (int jj = 0; jj < 4; ++jj) {
      int tr = w * 32 + jj * 8 + rl;
      int ct = colBase + tr;
      int pr = ((ct & 63) << 6) | (ct >> 6);  // Wm row for hyper-col ct
      const unsigned short* ga = A + (size_t)(rowBase + tr) * K + kt + kbg * 8;
      const unsigned short* gb = Wmb + (size_t)pr * K + kt + kbg * 8;
      __builtin_amdgcn_global_load_lds(
          (const __attribute__((address_space(1))) void*)ga,
          (__attribute__((address_space(3))) void*)&As[(w * 32 + jj * 8) * 64],
          16, 0, 0);
      __builtin_amdgcn_global_load_lds(
          (const __attribute__((address_space(1))) void*)gb,
          (__attribute__((address_space(3))) void*)&Bs[(w * 32 + jj * 8) * 64],
          16, 0, 0);
    }
    __syncthreads();

#pragma unroll
    for (int ks = 0; ks < 2; ++ks) {
      bf16x8_t a[4], b[4];
#pragma unroll
      for (int i = 0; i < 4; i++) {
        int m = wrow0 + i * 16 + fr;
        int slot = (ks * 4 + quad) ^ (m & 7);
        a[i] = *(const bf16x8_t*)&As[m * 64 + slot * 8];
      }
#pragma unroll
      for (int j = 0; j < 4; j++) {
        int n = wcol0 + j * 16 + fr;
        int slot = (ks * 4 + quad) ^ (n & 7);
        b[j] = *(const bf16x8_t*)&Bs[n * 64 + slot * 8];
      }
#pragma unroll
      for (int i = 0; i < 4; i++)
#pragma unroll
        for (int j = 0; j < 4; j++)
          acc[i][j] = __builtin_amdgcn_mfma_f32_16x16x32_bf16(a[i], b[j],
                                                              acc[i][j], 0, 0, 0);
    }
  }

  // ---- fused contraction epilogue ----
  __syncthreads();

  // stage u transposed: u_t[r][row], stride 136 to spread banks
  {
    int row = tid >> 1;
    int c0 = (tid & 1) * 32;
    const unsigned short* up = ug + (size_t)(rowBase + row) * 64 + c0;
    bf16x8_t v0 = *(const bf16x8_t*)(up);
    bf16x8_t v1 = *(const bf16x8_t*)(up + 8);
    bf16x8_t v2 = *(const bf16x8_t*)(up + 16);
    bf16x8_t v3 = *(const bf16x8_t*)(up + 24);
#pragma unroll
    for (int m = 0; m < 8; m++) {
      smem[(c0 + m) * 136 + row] = (unsigned short)v0[m];
      smem[(c0 + 8 + m) * 136 + row] = (unsigned short)v1[m];
      smem[(c0 + 16 + m) * 136 + row] = (unsigned short)v2[m];
      smem[(c0 + 24 + m) * 136 + row] = (unsigned short)v3[m];
    }
  }
  __syncthreads();

  const int s = blockIdx.x * 2 + (w >> 1);
  float bmv[4];
#pragma unroll
  for (int j = 0; j < 4; j++) bmv[j] = bm[(j * 16 + fr) * 64 + s];

#pragma unroll
  for (int i = 0; i < 4; i++) {
    int row0 = wrow0 + i * 16 + quad * 4;
    bf16x4_t uv[4];
#pragma unroll
    for (int j = 0; j < 4; j++)
      uv[j] = *(const bf16x4_t*)&smem[(j * 16 + fr) * 136 + row0];
#pragma unroll
    for (int r = 0; r < 4; r++) {
      float p = 0.f;
#pragma unroll
      for (int j = 0; j < 4; j++)
        p += bf2f((unsigned short)uv[j][r]) * (acc[i][j][r] + bmv[j]);
      p += __shfl_xor(p, 1, 64);
      p += __shfl_xor(p, 2, 64);
      p += __shfl_xor(p, 4, 64);
      p += __shfl_xor(p, 8, 64);
      if (fr == 0)
        h_out[(size_t)(rowBase + row0 + r) * 64 + s] = f2bf(p);
    }
  }
}

// ---------------------------------------------------------------------------
extern "C" void kernel_launch(void* const* d_in, const int* in_sizes, int n_in,
                              void* d_out, int out_size, void* d_ws,
                              size_t ws_size, hipStream_t stream) {
  const float* x = (const float*)d_in[0];
  const float* Wm[3] = {(const float*)d_in[1], (const float*)d_in[6], (const float*)d_in[11]};
  const float* bm[3] = {(const float*)d_in[2], (const float*)d_in[7], (const float*)d_in[12]};
  const float* U[3]  = {(const float*)d_in[3], (const float*)d_in[8], (const float*)d_in[13]};
  const float* V[3]  = {(const float*)d_in[4], (const float*)d_in[9], (const float*)d_in[14]};
  const float* bs[3] = {(const float*)d_in[5], (const float*)d_in[10], (const float*)d_in[15]};

  char* p = (char*)d_ws;
  unsigned short* xb = (unsigned short*)p;  p += 8192UL * 1024 * 2;
  unsigned short* act = (unsigned short*)p; p += 8192UL * 1024 * 2;
  unsigned short* Wmb[3];
  for (int l = 0; l < 3; l++) { Wmb[l] = (unsigned short*)p; p += 4096UL * 1024 * 2; }
  unsigned short* Ub[3];
  for (int l = 0; l < 3; l++) { Ub[l] = (unsigned short*)p; p += 64UL * 1024 * 2; }
  unsigned short* Vb[3];
  for (int l = 0; l < 3; l++) { Vb[l] = (unsigned short*)p; p += 1024UL * 64 * 2; }
  unsigned short* hb = (unsigned short*)p;  p += 8192UL * 64 * 2;
  unsigned short* ug = (unsigned short*)p;  p += 8192UL * 64 * 2;
  float* ug_part = (float*)p;               p += 4UL * 8192 * 64 * 4;

  // one dispatch: convert everything to bf16
  CvtTab t;
  t.src[0] = x;  t.dst[0] = xb;
  for (int l = 0; l < 3; l++) { t.src[1 + l] = Wm[l]; t.dst[1 + l] = Wmb[l]; }
  for (int l = 0; l < 3; l++) { t.src[4 + l] = U[l];  t.dst[4 + l] = Ub[l]; }
  for (int l = 0; l < 3; l++) { t.src[7 + l] = V[l];  t.dst[7 + l] = Vb[l]; }
  // sizes in blocks of 256 vec4s: x=8192, Wm=4096 each, U=V=64 each
  int bs_tab[10] = {8192, 4096, 4096, 4096, 64, 64, 64, 64, 64, 64};
  int acc_b = 0;
  for (int s = 0; s < 10; s++) { t.bstart[s] = acc_b; acc_b += bs_tab[s]; }
  cvt_all_k<<<acc_b, 256, 0, stream>>>(t);  // acc_b = 20864

  const unsigned short* cur = xb;
  for (int l = 0; l < 3; l++) {
    // u = cur @ U^T via split-K (4 slices) + reduce
    u_splitk<<<dim3(4, 64), 256, 0, stream>>>(cur, Ub[l], ug_part);
    u_reduce_k<<<512, 256, 0, stream>>>(ug_part, ug);
    // fused: h = einsum('br,brs->bs', u, cur@Wm^T + bm)
    gemm_fused<<<dim3(32, 64), 256, 0, stream>>>(cur, Wmb[l], ug, bm[l], hb);
    if (l < 2) {
      gemm_bt<0, 1, 1><<<dim3(8, 64), 256, 0, stream>>>(
          hb, Vb[l], bs[l], act, 8192, 1024, 64);
      cur = act;
    } else {
      gemm_bt<1, 0, 1><<<dim3(8, 64), 256, 0, stream>>>(
          hb, Vb[2], bs[2], d_out, 8192, 1024, 64);
    }
  }
}

// Round 4
// 420.916 us; speedup vs baseline: 1.2642x; 1.0028x over previous
//
#include <hip/hip_runtime.h>
#include <stdint.h>

typedef short bf16x8_t __attribute__((ext_vector_type(8)));
typedef short bf16x4_t __attribute__((ext_vector_type(4)));
typedef float f32x4_t __attribute__((ext_vector_type(4)));
typedef unsigned short u16x4_t __attribute__((ext_vector_type(4)));

#define DEV static __device__ __forceinline__

DEV float bf2f(unsigned short u) {
  union { unsigned int i; float f; } v; v.i = ((unsigned int)u) << 16; return v.f;
}
DEV unsigned short f2bf(float f) {
  union { float f; unsigned int i; } v; v.f = f;
  unsigned int x = v.i;
  unsigned int lsb = (x >> 16) & 1u;
  x += 0x7fffu + lsb;
  return (unsigned short)(x >> 16);
}

// ---------------------------------------------------------------------------
// One dispatch converting ALL fp32 inputs to bf16. Segment boundaries are all
// multiples of 256 vec4s, so `seg` is block-uniform (stays scalar).
struct CvtTab {
  const float* src[10];
  unsigned short* dst[10];
  int bstart[10];  // segment start, in BLOCKS (256 vec4 each)
};

__global__ __launch_bounds__(256) void cvt_all_k(CvtTab t) {
  int bi = blockIdx.x;
  int seg = 0;
#pragma unroll
  for (int s = 1; s < 10; s++) seg += (bi >= t.bstart[s]) ? 1 : 0;
  int local = (bi - t.bstart[seg]) * 256 + threadIdx.x;
  const float* src = t.src[seg];
  unsigned short* dst = t.dst[seg];
  float4 v = ((const float4*)src)[local];
  u16x4_t o = { f2bf(v.x), f2bf(v.y), f2bf(v.z), f2bf(v.w) };
  *(u16x4_t*)&dst[local * 4] = o;
}

// ---------------------------------------------------------------------------
// Split-K u-GEMM (layer 0 only): part[kslice] = A-rows @ U^T over a K-slice.
__global__ __launch_bounds__(256, 2) void u_splitk(
    const unsigned short* __restrict__ A,   // [8192 x 1024] bf16
    const unsigned short* __restrict__ Ub,  // [64 x 1024] bf16
    float* __restrict__ part) {             // [4][8192][64] fp32
  __shared__ unsigned short As[128 * 64];
  __shared__ unsigned short Us[64 * 64];

  const int tid = threadIdx.x;
  const int lane = tid & 63;
  const int w = tid >> 6;
  const int rowBase = blockIdx.y * 128;
  const int kBase = blockIdx.x * 256;

  const int rl = lane >> 3;
  const int kbs = lane & 7;
  const int kbg = kbs ^ rl;
  const int fr = lane & 15;
  const int quad = lane >> 4;

  f32x4_t acc[2][4];
#pragma unroll
  for (int i = 0; i < 2; i++)
#pragma unroll
    for (int j = 0; j < 4; j++) acc[i][j] = f32x4_t{0.f, 0.f, 0.f, 0.f};

  for (int kt = kBase; kt < kBase + 256; kt += 64) {
    __syncthreads();
#pragma unroll
    for (int jj = 0; jj < 4; ++jj) {
      int tr = w * 32 + jj * 8 + rl;
      const unsigned short* ga = A + (size_t)(rowBase + tr) * 1024 + kt + kbg * 8;
      __builtin_amdgcn_global_load_lds(
          (const __attribute__((address_space(1))) void*)ga,
          (__attribute__((address_space(3))) void*)&As[(w * 32 + jj * 8) * 64],
          16, 0, 0);
    }
#pragma unroll
    for (int jj = 0; jj < 2; ++jj) {
      int tr = w * 16 + jj * 8 + rl;
      const unsigned short* gu = Ub + (size_t)tr * 1024 + kt + kbg * 8;
      __builtin_amdgcn_global_load_lds(
          (const __attribute__((address_space(1))) void*)gu,
          (__attribute__((address_space(3))) void*)&Us[(w * 16 + jj * 8) * 64],
          16, 0, 0);
    }
    __syncthreads();

#pragma unroll
    for (int ks = 0; ks < 2; ++ks) {
      bf16x8_t a[2], b[4];
#pragma unroll
      for (int i = 0; i < 2; i++) {
        int m = w * 32 + i * 16 + fr;
        int slot = (ks * 4 + quad) ^ (m & 7);
        a[i] = *(const bf16x8_t*)&As[m * 64 + slot * 8];
      }
#pragma unroll
      for (int j = 0; j < 4; j++) {
        int n = j * 16 + fr;
        int slot = (ks * 4 + quad) ^ (n & 7);
        b[j] = *(const bf16x8_t*)&Us[n * 64 + slot * 8];
      }
#pragma unroll
      for (int i = 0; i < 2; i++)
#pragma unroll
        for (int j = 0; j < 4; j++)
          acc[i][j] = __builtin_amdgcn_mfma_f32_16x16x32_bf16(a[i], b[j],
                                                              acc[i][j], 0, 0, 0);
    }
  }

  float* pp = part + ((size_t)blockIdx.x * 8192 + rowBase) * 64;
#pragma unroll
  for (int i = 0; i < 2; i++)
#pragma unroll
    for (int j = 0; j < 4; j++)
#pragma unroll
      for (int r = 0; r < 4; r++) {
        int row = w * 32 + i * 16 + quad * 4 + r;
        pp[(size_t)row * 64 + j * 16 + fr] = acc[i][j][r];
      }
}

// sum 4 K-slices -> bf16 u [8192 x 64]
__global__ __launch_bounds__(256) void u_reduce_k(
    const float* __restrict__ part, unsigned short* __restrict__ ug) {
  int i = blockIdx.x * 256 + threadIdx.x;  // vec4 idx over 131072
  float4 s0 = ((const float4*)part)[i];
  float4 s1 = ((const float4*)part)[i + 131072];
  float4 s2 = ((const float4*)part)[i + 262144];
  float4 s3 = ((const float4*)part)[i + 393216];
  u16x4_t o = { f2bf(s0.x + s1.x + s2.x + s3.x),
                f2bf(s0.y + s1.y + s2.y + s3.y),
                f2bf(s0.z + s1.z + s2.z + s3.z),
                f2bf(s0.w + s1.w + s2.w + s3.w) };
  *(u16x4_t*)&ug[i * 4] = o;
}

// ---------------------------------------------------------------------------
// Generic GEMM: C[M x N] = A[M x K] * B[N x K]^T (bf16 in, K-contiguous).
// Used only for the final layer (fp32 out, K=64).
template <int OUTF32, int RELU, int BIAS>
__global__ __launch_bounds__(256, 2) void gemm_bt(
    const unsigned short* __restrict__ A, const unsigned short* __restrict__ B,
    const float* __restrict__ bias, void* __restrict__ Cout,
    int M, int N, int K) {
  __shared__ unsigned short As[128 * 64];
  __shared__ unsigned short Bs[128 * 64];

  const int tid = threadIdx.x;
  const int lane = tid & 63;
  const int w = tid >> 6;
  const int wrow0 = (w & 1) * 64;
  const int wcol0 = (w >> 1) * 64;
  const int rowBase = blockIdx.y * 128;
  const int colBase = blockIdx.x * 128;

  const int rl = lane >> 3;
  const int kbs = lane & 7;
  const int kbg = kbs ^ rl;
  const int fr = lane & 15;
  const int quad = lane >> 4;

  f32x4_t acc[4][4];
#pragma unroll
  for (int i = 0; i < 4; i++)
#pragma unroll
    for (int j = 0; j < 4; j++) acc[i][j] = f32x4_t{0.f, 0.f, 0.f, 0.f};

  for (int kt = 0; kt < K; kt += 64) {
    __syncthreads();
#pragma unroll
    for (int jj = 0; jj < 4; ++jj) {
      int tr = w * 32 + jj * 8 + rl;
      const unsigned short* ga = A + (size_t)(rowBase + tr) * K + kt + kbg * 8;
      const unsigned short* gb = B + (size_t)(colBase + tr) * K + kt + kbg * 8;
      __builtin_amdgcn_global_load_lds(
          (const __attribute__((address_space(1))) void*)ga,
          (__attribute__((address_space(3))) void*)&As[(w * 32 + jj * 8) * 64],
          16, 0, 0);
      __builtin_amdgcn_global_load_lds(
          (const __attribute__((address_space(1))) void*)gb,
          (__attribute__((address_space(3))) void*)&Bs[(w * 32 + jj * 8) * 64],
          16, 0, 0);
    }
    __syncthreads();

#pragma unroll
    for (int ks = 0; ks < 2; ++ks) {
      bf16x8_t a[4], b[4];
#pragma unroll
      for (int i = 0; i < 4; i++) {
        int m = wrow0 + i * 16 + fr;
        int slot = (ks * 4 + quad) ^ (m & 7);
        a[i] = *(const bf16x8_t*)&As[m * 64 + slot * 8];
      }
#pragma unroll
      for (int j = 0; j < 4; j++) {
        int n = wcol0 + j * 16 + fr;
        int slot = (ks * 4 + quad) ^ (n & 7);
        b[j] = *(const bf16x8_t*)&Bs[n * 64 + slot * 8];
      }
#pragma unroll
      for (int i = 0; i < 4; i++)
#pragma unroll
        for (int j = 0; j < 4; j++)
          acc[i][j] = __builtin_amdgcn_mfma_f32_16x16x32_bf16(a[i], b[j],
                                                              acc[i][j], 0, 0, 0);
    }
  }

#pragma unroll
  for (int j = 0; j < 4; j++) {
    int col = colBase + wcol0 + j * 16 + fr;
    float bv = BIAS ? bias[col] : 0.0f;
#pragma unroll
    for (int i = 0; i < 4; i++) {
#pragma unroll
      for (int r = 0; r < 4; r++) {
        int row = rowBase + wrow0 + i * 16 + quad * 4 + r;
        float v = acc[i][j][r] + bv;
        if (RELU) v = v > 0.f ? v : 0.f;
        if (OUTF32)
          ((float*)Cout)[(size_t)row * N + col] = v;
        else
          ((unsigned short*)Cout)[(size_t)row * N + col] = f2bf(v);
      }
    }
  }
}

// ---------------------------------------------------------------------------
// Fused hyper-GEMM + per-sample contraction (col' = s*64+r permutation).
__global__ __launch_bounds__(256, 2) void gemm_fused(
    const unsigned short* __restrict__ A,    // [8192 x 1024] bf16
    const unsigned short* __restrict__ Wmb,  // [4096 x 1024] bf16
    const unsigned short* __restrict__ ug,   // [8192 x 64] bf16
    const float* __restrict__ bm,            // [4096] fp32
    unsigned short* __restrict__ h_out) {    // [8192 x 64] bf16
  __shared__ unsigned short smem[16384];
  unsigned short* As = smem;
  unsigned short* Bs = smem + 8192;
  const int K = 1024;

  const int tid = threadIdx.x;
  const int lane = tid & 63;
  const int w = tid >> 6;
  const int wrow0 = (w & 1) * 64;
  const int wcol0 = (w >> 1) * 64;
  const int rowBase = blockIdx.y * 128;
  const int colBase = blockIdx.x * 128;

  const int rl = lane >> 3;
  const int kbs = lane & 7;
  const int kbg = kbs ^ rl;
  const int fr = lane & 15;
  const int quad = lane >> 4;

  f32x4_t acc[4][4];
#pragma unroll
  for (int i = 0; i < 4; i++)
#pragma unroll
    for (int j = 0; j < 4; j++) acc[i][j] = f32x4_t{0.f, 0.f, 0.f, 0.f};

  for (int kt = 0; kt < K; kt += 64) {
    __syncthreads();
#pragma unroll
    for (int jj = 0; jj < 4; ++jj) {
      int tr = w * 32 + jj * 8 + rl;
      int ct = colBase + tr;
      int pr = ((ct & 63) << 6) | (ct >> 6);  // Wm row for hyper-col ct
      const unsigned short* ga = A + (size_t)(rowBase + tr) * K + kt + kbg * 8;
      const unsigned short* gb = Wmb + (size_t)pr * K + kt + kbg * 8;
      __builtin_amdgcn_global_load_lds(
          (const __attribute__((address_space(1))) void*)ga,
          (__attribute__((address_space(3))) void*)&As[(w * 32 + jj * 8) * 64],
          16, 0, 0);
      __builtin_amdgcn_global_load_lds(
          (const __attribute__((address_space(1))) void*)gb,
          (__attribute__((address_space(3))) void*)&Bs[(w * 32 + jj * 8) * 64],
          16, 0, 0);
    }
    __syncthreads();

#pragma unroll
    for (int ks = 0; ks < 2; ++ks) {
      bf16x8_t a[4], b[4];
#pragma unroll
      for (int i = 0; i < 4; i++) {
        int m = wrow0 + i * 16 + fr;
        int slot = (ks * 4 + quad) ^ (m & 7);
        a[i] = *(const bf16x8_t*)&As[m * 64 + slot * 8];
      }
#pragma unroll
      for (int j = 0; j < 4; j++) {
        int n = wcol0 + j * 16 + fr;
        int slot = (ks * 4 + quad) ^ (n & 7);
        b[j] = *(const bf16x8_t*)&Bs[n * 64 + slot * 8];
      }
#pragma unroll
      for (int i = 0; i < 4; i++)
#pragma unroll
        for (int j = 0; j < 4; j++)
          acc[i][j] = __builtin_amdgcn_mfma_f32_16x16x32_bf16(a[i], b[j],
                                                              acc[i][j], 0, 0, 0);
    }
  }

  // ---- fused contraction epilogue ----
  __syncthreads();

  // stage u transposed: u_t[r][row], stride 136 to spread banks
  {
    int row = tid >> 1;
    int c0 = (tid & 1) * 32;
    const unsigned short* up = ug + (size_t)(rowBase + row) * 64 + c0;
    bf16x8_t v0 = *(const bf16x8_t*)(up);
    bf16x8_t v1 = *(const bf16x8_t*)(up + 8);
    bf16x8_t v2 = *(const bf16x8_t*)(up + 16);
    bf16x8_t v3 = *(const bf16x8_t*)(up + 24);
#pragma unroll
    for (int m = 0; m < 8; m++) {
      smem[(c0 + m) * 136 + row] = (unsigned short)v0[m];
      smem[(c0 + 8 + m) * 136 + row] = (unsigned short)v1[m];
      smem[(c0 + 16 + m) * 136 + row] = (unsigned short)v2[m];
      smem[(c0 + 24 + m) * 136 + row] = (unsigned short)v3[m];
    }
  }
  __syncthreads();

  const int s = blockIdx.x * 2 + (w >> 1);
  float bmv[4];
#pragma unroll
  for (int j = 0; j < 4; j++) bmv[j] = bm[(j * 16 + fr) * 64 + s];

#pragma unroll
  for (int i = 0; i < 4; i++) {
    int row0 = wrow0 + i * 16 + quad * 4;
    bf16x4_t uv[4];
#pragma unroll
    for (int j = 0; j < 4; j++)
      uv[j] = *(const bf16x4_t*)&smem[(j * 16 + fr) * 136 + row0];
#pragma unroll
    for (int r = 0; r < 4; r++) {
      float p = 0.f;
#pragma unroll
      for (int j = 0; j < 4; j++)
        p += bf2f((unsigned short)uv[j][r]) * (acc[i][j][r] + bmv[j]);
      p += __shfl_xor(p, 1, 64);
      p += __shfl_xor(p, 2, 64);
      p += __shfl_xor(p, 4, 64);
      p += __shfl_xor(p, 8, 64);
      if (fr == 0)
        h_out[(size_t)(rowBase + row0 + r) * 64 + s] = f2bf(p);
    }
  }
}

// ---------------------------------------------------------------------------
// Fused V-GEMM + next-layer u-GEMM:
//   t = relu(h @ V^T + b)   [written to act, bf16]
//   u = t @ Un^T            [written to u_out, bf16]
// Block = 16 sample-rows, 4 waves; wave w owns t-cols [w*256, w*256+256),
// streamed in 4 chunks of 64. Per chunk: MFMA1 (h x V) -> C-layout regs ->
// relu/bias -> LDS (A-layout transpose, per-wave private region) ->
// b128 act store + MFMA2 (t x Un) accumulating u. Single __syncthreads for
// the cross-wave u reduction. All operands read direct from L2 (V,U hot).
__global__ __launch_bounds__(256, 2) void vu_fused(
    const unsigned short* __restrict__ h,    // [8192 x 64] bf16
    const unsigned short* __restrict__ Vb,   // [1024 x 64] bf16
    const float* __restrict__ bias,          // [1024] fp32
    const unsigned short* __restrict__ Un,   // [64 x 1024] bf16 (next U)
    unsigned short* __restrict__ act,        // [8192 x 1024] bf16
    unsigned short* __restrict__ u_out) {    // [8192 x 64] bf16
  __shared__ unsigned short tlds[4 * 16 * 72];  // per-wave t chunk [16][72]
  __shared__ float upart[4 * 16 * 68];          // per-wave u partial [16][68]

  const int tid = threadIdx.x;
  const int lane = tid & 63;
  const int w = tid >> 6;
  const int fr = lane & 15;
  const int quad = lane >> 4;
  const int rowBase = blockIdx.x * 16;

  unsigned short* tl = &tlds[w * 16 * 72];

  // h A-fragments (K=64 -> 2 ksteps), direct from global
  bf16x8_t ah0 = *(const bf16x8_t*)&h[(size_t)(rowBase + fr) * 64 + quad * 8];
  bf16x8_t ah1 = *(const bf16x8_t*)&h[(size_t)(rowBase + fr) * 64 + 32 + quad * 8];

  f32x4_t uacc[4];
#pragma unroll
  for (int n = 0; n < 4; n++) uacc[n] = f32x4_t{0.f, 0.f, 0.f, 0.f};

  for (int it = 0; it < 4; ++it) {
    const int cb = w * 256 + it * 64;  // t-col chunk base

    // MFMA1: t_chunk[16 rows x 64 cols] = h @ V^T
    f32x4_t tacc[4];
#pragma unroll
    for (int nt = 0; nt < 4; nt++) {
      const unsigned short* vrow = Vb + (size_t)(cb + nt * 16 + fr) * 64;
      bf16x8_t b0 = *(const bf16x8_t*)&vrow[quad * 8];
      bf16x8_t b1 = *(const bf16x8_t*)&vrow[32 + quad * 8];
      f32x4_t z = {0.f, 0.f, 0.f, 0.f};
      z = __builtin_amdgcn_mfma_f32_16x16x32_bf16(ah0, b0, z, 0, 0, 0);
      tacc[nt] = __builtin_amdgcn_mfma_f32_16x16x32_bf16(ah1, b1, z, 0, 0, 0);
    }

    // bias + relu + bf16, stage to LDS in [m][k] A-layout
#pragma unroll
    for (int nt = 0; nt < 4; nt++) {
      float bv = bias[cb + nt * 16 + fr];
#pragma unroll
      for (int r = 0; r < 4; r++) {
        float v = tacc[nt][r] + bv;
        v = v > 0.f ? v : 0.f;
        tl[(quad * 4 + r) * 72 + nt * 16 + fr] = f2bf(v);
      }
    }

    // act store: re-read LDS as row-chunks for b128 coalesced stores
    {
      int m2 = lane >> 2;
      int kc = (lane & 3) * 16;
      bf16x8_t t0 = *(const bf16x8_t*)&tl[m2 * 72 + kc];
      bf16x8_t t1 = *(const bf16x8_t*)&tl[m2 * 72 + kc + 8];
      unsigned short* ap = act + (size_t)(rowBase + m2) * 1024 + cb + kc;
      *(bf16x8_t*)ap = t0;
      *(bf16x8_t*)(ap + 8) = t1;
    }

    // MFMA2: u += t_chunk @ Un^T (K = this 64-col chunk)
#pragma unroll
    for (int ks = 0; ks < 2; ++ks) {
      bf16x8_t at = *(const bf16x8_t*)&tl[fr * 72 + ks * 32 + quad * 8];
#pragma unroll
      for (int n = 0; n < 4; n++) {
        bf16x8_t bu = *(const bf16x8_t*)&Un[(size_t)(n * 16 + fr) * 1024 + cb +
                                            ks * 32 + quad * 8];
        uacc[n] = __builtin_amdgcn_mfma_f32_16x16x32_bf16(at, bu, uacc[n], 0, 0, 0);
      }
    }
  }

  // cross-wave reduction of u partials
  {
    float* up = &upart[w * 16 * 68];
#pragma unroll
    for (int n = 0; n < 4; n++)
#pragma unroll
      for (int r = 0; r < 4; r++)
        up[(quad * 4 + r) * 68 + n * 16 + fr] = uacc[n][r];
  }
  __syncthreads();
  {
    int m = tid >> 4;
    int c0 = (tid & 15) * 4;
    f32x4_t s = {0.f, 0.f, 0.f, 0.f};
#pragma unroll
    for (int wv = 0; wv < 4; wv++)
      s += *(const f32x4_t*)&upart[wv * 16 * 68 + m * 68 + c0];
    u16x4_t o = { f2bf(s[0]), f2bf(s[1]), f2bf(s[2]), f2bf(s[3]) };
    *(u16x4_t*)&u_out[(size_t)(rowBase + m) * 64 + c0] = o;
  }
}

// ---------------------------------------------------------------------------
extern "C" void kernel_launch(void* const* d_in, const int* in_sizes, int n_in,
                              void* d_out, int out_size, void* d_ws,
                              size_t ws_size, hipStream_t stream) {
  const float* x = (const float*)d_in[0];
  const float* Wm[3] = {(const float*)d_in[1], (const float*)d_in[6], (const float*)d_in[11]};
  const float* bm[3] = {(const float*)d_in[2], (const float*)d_in[7], (const float*)d_in[12]};
  const float* U[3]  = {(const float*)d_in[3], (const float*)d_in[8], (const float*)d_in[13]};
  const float* V[3]  = {(const float*)d_in[4], (const float*)d_in[9], (const float*)d_in[14]};
  const float* bs[3] = {(const float*)d_in[5], (const float*)d_in[10], (const float*)d_in[15]};

  char* p = (char*)d_ws;
  unsigned short* xb = (unsigned short*)p;  p += 8192UL * 1024 * 2;
  unsigned short* act = (unsigned short*)p; p += 8192UL * 1024 * 2;
  unsigned short* Wmb[3];
  for (int l = 0; l < 3; l++) { Wmb[l] = (unsigned short*)p; p += 4096UL * 1024 * 2; }
  unsigned short* Ub[3];
  for (int l = 0; l < 3; l++) { Ub[l] = (unsigned short*)p; p += 64UL * 1024 * 2; }
  unsigned short* Vb[3];
  for (int l = 0; l < 3; l++) { Vb[l] = (unsigned short*)p; p += 1024UL * 64 * 2; }
  unsigned short* hb = (unsigned short*)p;  p += 8192UL * 64 * 2;
  unsigned short* ug = (unsigned short*)p;  p += 8192UL * 64 * 2;
  float* ug_part = (float*)p;               p += 4UL * 8192 * 64 * 4;

  // one dispatch: convert everything to bf16
  CvtTab t;
  t.src[0] = x;  t.dst[0] = xb;
  for (int l = 0; l < 3; l++) { t.src[1 + l] = Wm[l]; t.dst[1 + l] = Wmb[l]; }
  for (int l = 0; l < 3; l++) { t.src[4 + l] = U[l];  t.dst[4 + l] = Ub[l]; }
  for (int l = 0; l < 3; l++) { t.src[7 + l] = V[l];  t.dst[7 + l] = Vb[l]; }
  int bs_tab[10] = {8192, 4096, 4096, 4096, 64, 64, 64, 64, 64, 64};
  int acc_b = 0;
  for (int s = 0; s < 10; s++) { t.bstart[s] = acc_b; acc_b += bs_tab[s]; }
  cvt_all_k<<<acc_b, 256, 0, stream>>>(t);  // acc_b = 20864

  // layer 0 u: x @ U0^T via split-K + reduce
  u_splitk<<<dim3(4, 64), 256, 0, stream>>>(xb, Ub[0], ug_part);
  u_reduce_k<<<512, 256, 0, stream>>>(ug_part, ug);

  const unsigned short* cur = xb;
  for (int l = 0; l < 3; l++) {
    // fused: h = einsum('br,brs->bs', u, cur@Wm^T + bm)
    gemm_fused<<<dim3(32, 64), 256, 0, stream>>>(cur, Wmb[l], ug, bm[l], hb);
    if (l < 2) {
      // act = relu(h@V^T + b); u(next) = act @ U[l+1]^T — one kernel
      vu_fused<<<512, 256, 0, stream>>>(hb, Vb[l], bs[l], Ub[l + 1], act, ug);
      cur = act;
    } else {
      gemm_bt<1, 0, 1><<<dim3(8, 64), 256, 0, stream>>>(
          hb, Vb[2], bs[2], d_out, 8192, 1024, 64);
    }
  }
}